// Round 17
// baseline (484.397 us; speedup 1.0000x reference)
//
#include <hip/hip_runtime.h>
#include <hip/hip_bf16.h>

// StyleLayer: modulated conv3x3 as bf16 MFMA implicit GEMM (demod folded into
// input/output scales) + fused polyphase upfirdn(up2)->lrelu/clamp->upfirdn(down2).
// B=8, CIN=COUT=SDIM=512, H=W=64, K=3, taps=12, out 64x64. Conv out 66x66 (=4356 px).

#define B_    8
#define CIN_  512
#define COUT_ 512
#define SDIM_ 512
#define H_    64
#define W_    64
#define HO_   66
#define NPIX  4356          // 66*66
#define XP    68            // padded input spatial (origin shift 2)

typedef short s8v  __attribute__((ext_vector_type(8)));   // 8 bf16 in 4 VGPRs
typedef float f4v  __attribute__((ext_vector_type(4)));

#define WAITV4() asm volatile("s_waitcnt vmcnt(4)" ::: "memory")
#define WAITV3() asm volatile("s_waitcnt vmcnt(3)" ::: "memory")
#define WAITV0() asm volatile("s_waitcnt vmcnt(0)" ::: "memory")

// ---------------- s[b,c] = w @ (aw/sqrt(SDIM)).T + ab ----------------
__global__ __launch_bounds__(256) void k_style_s(
    const float* __restrict__ w, const float* __restrict__ aw,
    const float* __restrict__ ab, float* __restrict__ s) {
    const int t  = blockIdx.x * 4 + (threadIdx.x >> 6);   // 4096 outputs
    const int ln = threadIdx.x & 63;
    const int b = t >> 9, c = t & 511;
    const float* wp = w + b * SDIM_;
    const float* ap = aw + (size_t)c * SDIM_;
    float acc = 0.f;
    #pragma unroll
    for (int j = 0; j < 8; ++j) { int k = ln + 64 * j; acc += wp[k] * ap[k]; }
    #pragma unroll
    for (int off = 32; off; off >>= 1) acc += __shfl_down(acc, off, 64);
    if (ln == 0) s[t] = acc * 0.044194173824159216f + ab[c];
}

// ---------------- coef[b,o] = scale * rsqrt(sum_c s^2 r) * rsqrt(ema) ----------------
__global__ __launch_bounds__(256) void k_style_coef(
    const float* __restrict__ s, const float* __restrict__ r,
    const float* __restrict__ ema, float* __restrict__ coef) {
    const int t  = blockIdx.x * 4 + (threadIdx.x >> 6);   // 4096 outputs
    const int ln = threadIdx.x & 63;
    const int b = t >> 9, o = t & 511;
    const float* sp = s + b * 512;
    const float* rp = r + (size_t)o * 512;
    float acc = 0.f;
    #pragma unroll
    for (int j = 0; j < 8; ++j) {
        int k = ln + 64 * j;
        float sv = sp[k];
        acc += sv * sv * rp[k];
    }
    #pragma unroll
    for (int off = 32; off; off >>= 1) acc += __shfl_down(acc, off, 64);
    if (ln == 0) {
        float d  = rsqrtf(acc * (1.0f / 4608.0f) + 1e-8f);
        coef[t] = d * rsqrtf(ema[0]) * 0.014731391274719739f;
    }
}

// ---------------- wb[tap][o][c] = bf16(cw[o][c][tap]);  r[o*512+c] = sum_tap cw^2 ----
__global__ __launch_bounds__(256) void k_prep_w(const float* __restrict__ cw,
                                                __hip_bfloat16* __restrict__ wb,
                                                float* __restrict__ r) {
    __shared__ float sm[2304];
    const int base = blockIdx.x * 256;                // pair index o*512+c; 1024 blocks
    const int tid  = threadIdx.x;
    const float* src = cw + (size_t)base * 9;
    for (int i = tid; i < 2304; i += 256) sm[i] = src[i];
    __syncthreads();
    float a = 0.f;
    ushort u[9];
    #pragma unroll
    for (int k = 0; k < 9; ++k) {
        float v = sm[tid * 9 + k];                    // 2-way bank alias: free
        a += v * v;
        __hip_bfloat16 h = __float2bfloat16(v);
        u[k] = *reinterpret_cast<ushort*>(&h);
    }
    r[base + tid] = a;
    ushort* wbu = reinterpret_cast<ushort*>(wb);
    #pragma unroll
    for (int tap = 0; tap < 9; ++tap)
        wbu[tap * 262144 + base + tid] = u[tap];
}

// ---------------- xt[b][y][x][c] = bf16(x[b][c][y-2][x-2] * s[b][c]), zero pad ----
__global__ __launch_bounds__(256) void k_prep_x(const float* __restrict__ x,
                                                const float* __restrict__ s,
                                                __hip_bfloat16* __restrict__ xt) {
    __shared__ float tile[64][65];
    const int y = blockIdx.x;            // 0..67
    const int b = blockIdx.y;
    const int tid = threadIdx.x;
    const bool yin = (y >= 2 && y < 66);
    __hip_bfloat16* orow = xt + ((size_t)(b * XP + y)) * XP * 512;
    for (int c0 = 0; c0 < 512; c0 += 64) {
        if (yin) {
            for (int i = tid; i < 64 * 64; i += 256) {
                int c = i >> 6, xx = i & 63;
                tile[c][xx] = x[(((size_t)b * 512 + c0 + c) * 64 + (y - 2)) * 64 + xx]
                              * s[b * 512 + c0 + c];
            }
        }
        __syncthreads();
        for (int j = tid; j < 68 * 8; j += 256) {     // 68 x-positions, 8 c-groups of 8
            int xx = j >> 3, cg = j & 7;
            bool xin = yin && (xx >= 2 && xx < 66);
            union { ushort u[8]; float4 f4; } pk;
            #pragma unroll
            for (int k = 0; k < 8; ++k) {
                float v = xin ? tile[cg * 8 + k][xx - 2] : 0.f;
                __hip_bfloat16 h = __float2bfloat16(v);
                pk.u[k] = *reinterpret_cast<ushort*>(&h);
            }
            *reinterpret_cast<float4*>(orow + (size_t)xx * 512 + c0 + cg * 8) = pk.f4;
        }
        __syncthreads();
    }
}

// ---------------- MFMA implicit-GEMM conv ----------------
// 256 o x 160 px tile (acc[4][5]): 448 tiles <= 512 block slots -> single
// dispatch round, max-CU-load 906->755 MFLOP. vs round-16: compute() loads
// ALL fragments upfront (af[4]+bfv[5], 9 overlapped ds_reads) before the 20
// MFMAs -- round-16's in-loop single-bv read serialized ds_read->MFMA chains
// (exposed ~120cy LDS latency 5x/step -> MfmaUtil 27%).
__device__ __forceinline__ void gload16u(const char* base, unsigned voff, void* l) {
    __builtin_amdgcn_global_load_lds(
        (const __attribute__((address_space(1))) unsigned*)(base + voff),
        (__attribute__((address_space(3))) unsigned*)l, 16, 0, 0);
}

__global__ __launch_bounds__(512, 4) void k_conv_mfma(
    const __hip_bfloat16* __restrict__ wb, const __hip_bfloat16* __restrict__ xt,
    const float* __restrict__ coef, const float* __restrict__ bias,
    __hip_bfloat16* __restrict__ y1)
{
    __shared__ __hip_bfloat16 lds[3][13312];          // [buf][A(8192) | B(5120)]

    // XCD-chunked bijection (448 = 8 x 56): each XCD gets 56 consecutive flat
    // ids = 2 (b,o0) groups x 28 px tiles -> one 2.25 MB A panel L2-resident.
    const int bid  = blockIdx.x;                      // 448 blocks
    const int flat = (bid & 7) * 56 + (bid >> 3);
    const int pi = flat % 28;
    const int t2 = flat / 28;                         // 0..15: (oi*8 + b)
    const int b  = t2 & 7;
    const int o0 = (t2 >> 3) * 256;
    const int p0 = (pi < 27) ? pi * 160 : (NPIX - 160);   // overlap tail tile

    const int tid = threadIdx.x, wv = tid >> 6, ln = tid & 63;
    const int wm = wv >> 1, wn = wv & 1;              // 4 o-quadrants x 2 px-halves

    // ---- per-lane 32-bit staging offsets (loop-invariant), uniform bases ----
    const char* wbB = (const char*)wb;
    const char* xtB = (const char*)(xt + (size_t)b * XP * XP * 512);
    const int srow = tid >> 2, ssl = tid & 3;         // A rows 0..127 per gload
    const unsigned swzs = (unsigned)((ssl ^ ((srow >> 1) & 3)) << 3);
    unsigned voffA0 = ((unsigned)(o0 + srow) * 512u + swzs) * 2u;
    unsigned voffA1 = ((unsigned)(o0 + 128 + srow) * 512u + swzs) * 2u;
    unsigned voffB0, voffB1 = 0;
    {
        int p = p0 + srow;                            // B rows 0..127
        int py = (int)(((unsigned)p * 63551u) >> 22); // p/66
        int px = p - py * 66;
        voffB0 = ((unsigned)(py * XP + px) * 512u + swzs) * 2u;
    }
    if (wv < 2) {                                     // B rows 128..159 (chunks 512+tid)
        int j2 = 512 + tid;
        int row2 = j2 >> 2, sl2 = j2 & 3;
        unsigned swz2 = (unsigned)((sl2 ^ ((row2 >> 1) & 3)) << 3);
        int p = p0 + row2;
        int py = (int)(((unsigned)p * 63551u) >> 22);
        int px = p - py * 66;
        voffB1 = ((unsigned)(py * XP + px) * 512u + swz2) * 2u;
    }

    // ---- per-lane LDS fragment byte offsets (loop-invariant) ----
    int aoff[4], boff[5];
    #pragma unroll
    for (int f = 0; f < 4; ++f) {
        int r  = wm * 64 + f * 16 + (ln & 15);
        aoff[f] = (r * 32 + (((ln >> 4) ^ ((r >> 1) & 3)) << 3)) * 2;
    }
    #pragma unroll
    for (int f = 0; f < 5; ++f) {
        int rb = wn * 80 + f * 16 + (ln & 15);
        boff[f] = (8192 + rb * 32 + (((ln >> 4) ^ ((rb >> 1) & 3)) << 3)) * 2;
    }

    f4v acc[4][5];
    #pragma unroll
    for (int fm = 0; fm < 4; ++fm)
        #pragma unroll
        for (int fn = 0; fn < 5; ++fn) acc[fm][fn] = (f4v){0.f, 0.f, 0.f, 0.f};

    auto stage = [&](int st, int buf) {               // buf is a literal at call sites
        int tap = st >> 4;                            // uniform -> SALU
        int ki  = (tap * 11) >> 5;                    // tap/3 for tap<9
        int kj  = tap - ki * 3;
        unsigned ccb  = (unsigned)(st & 15) << 6;     // c-chunk bytes
        unsigned offA = (unsigned)tap * 524288u + ccb;            // tap*512*512*2B
        unsigned offB = (unsigned)(ki * XP + kj) * 1024u + ccb;   // (ki*XP+kj)*512*2B
        __hip_bfloat16* dst = &lds[buf][0] + wv * 512;
        gload16u(wbB, voffA0 + offA, dst);            // A rows   0..127
        gload16u(wbB, voffA1 + offA, dst + 4096);     // A rows 128..255
        gload16u(xtB, voffB0 + offB, dst + 8192);     // B rows   0..127
        if (wv < 2)
            gload16u(xtB, voffB1 + offB, dst + 12288); // B rows 128..159
    };

    auto compute = [&](int buf) {                     // buf literal -> const LDS bases
        const char* base = (const char*)&lds[buf][0];
        s8v af[4], bfv[5];
        #pragma unroll
        for (int f = 0; f < 4; ++f)
            af[f] = *reinterpret_cast<const s8v*>(base + aoff[f]);
        #pragma unroll
        for (int f = 0; f < 5; ++f)
            bfv[f] = *reinterpret_cast<const s8v*>(base + boff[f]);
        #pragma unroll
        for (int fm = 0; fm < 4; ++fm)
            #pragma unroll
            for (int fn = 0; fn < 5; ++fn)
                acc[fm][fn] = __builtin_amdgcn_mfma_f32_16x16x32_bf16(
                    af[fm], bfv[fn], acc[fm][fn], 0, 0, 0);
    };

    stage(0, 0);
    stage(1, 1);

    // steps 0..140 in groups of 3; counted vmcnt keeps the next step's loads
    // in flight across every barrier (per-wave count: wv<2 -> 4, else 3).
    #pragma unroll 1
    for (int st = 0; st < 141; st += 3) {
        if (wv < 2) { WAITV4(); } else { WAITV3(); }
        __builtin_amdgcn_s_barrier();
        compute(0); stage(st + 2, 2);
        if (wv < 2) { WAITV4(); } else { WAITV3(); }
        __builtin_amdgcn_s_barrier();
        compute(1); stage(st + 3, 0);
        if (wv < 2) { WAITV4(); } else { WAITV3(); }
        __builtin_amdgcn_s_barrier();
        compute(2); stage(st + 4, 1);
    }
    // epilogue: steps 141 (buf0), 142 (buf1), 143 (buf2; staged here).
    if (wv < 2) { WAITV4(); } else { WAITV3(); }
    __builtin_amdgcn_s_barrier();
    compute(0); stage(143, 2);
    if (wv < 2) { WAITV4(); } else { WAITV3(); }
    __builtin_amdgcn_s_barrier();
    compute(1);
    WAITV0(); __builtin_amdgcn_s_barrier();
    compute(2);

    // C-write: y1[b][o][p] bf16 = acc*coef + bias
    #pragma unroll
    for (int fm = 0; fm < 4; ++fm) {
        #pragma unroll
        for (int fn = 0; fn < 5; ++fn) {
            int p = p0 + wn * 80 + fn * 16 + (ln & 15);
            int ob = o0 + wm * 64 + fm * 16 + (ln >> 4) * 4;
            #pragma unroll
            for (int jj = 0; jj < 4; ++jj) {
                int o = ob + jj;
                float v = acc[fm][fn][jj] * coef[b * 512 + o] + bias[o];
                y1[((size_t)(b * 512 + o)) * NPIX + p] = __float2bfloat16(v);
            }
        }
    }
}

// ---------------- fused upfirdn2(up2,pad(9,8)) -> lrelu*sqrt2,clamp -> upfirdn2(down2) ----
// 32x32 output tile. No integer div/mod in hot loops; polyphase even/odd pair
// sharing; phase-2 uses a per-column sliding register window; It/zt and hu/dh
// share LDS regions.
__global__ __launch_bounds__(256) void k_style_fir(
    const __hip_bfloat16* __restrict__ y1, const float* __restrict__ uf,
    const float* __restrict__ df, float* __restrict__ out)
{
    __shared__ float smA[5632];          // It[42][44] then zt[74][76]
    __shared__ float smB[3200];          // hu[42][76] then dh[74][36]
    float* It = smA;                     // stride 44
    float* hu = smB;                     // stride 76
    float* zt = smA;                     // stride 76
    float* dh = smB;                     // stride 36

    const int img = blockIdx.z;          // b*COUT + o
    const int oy0 = blockIdx.y * 32;
    const int ox0 = blockIdx.x * 32;
    const int tid = threadIdx.x;
    const __hip_bfloat16* I = y1 + (size_t)img * NPIX;

    float cu[12], cd[12];
    #pragma unroll
    for (int q = 0; q < 12; ++q) { cu[q] = uf[q]; cd[q] = df[q]; }

    const int ty = tid >> 5, tx = tid & 31;   // 8 x 32
    const int ty4 = tid >> 4, tx4 = tid & 15; // 16 x 16

    // phase 0: load It[42][42] <- y1 tile rows/cols [oy0-4, oy0+37]
    #pragma unroll
    for (int k = 0; k < 6; ++k) {
        int rr = ty + 8 * k; if (rr >= 42) break;
        int gy = oy0 - 4 + rr;
        bool yin = (gy >= 0 && gy < HO_);
        #pragma unroll
        for (int j = 0; j < 2; ++j) {
            int cc = tx + 32 * j; if (cc >= 42) continue;
            int gx = ox0 - 4 + cc;
            float v = 0.f;
            if (yin && gx >= 0 && gx < HO_) v = __bfloat162float(I[gy * HO_ + gx]);
            It[rr * 44 + cc] = v;
        }
    }
    __syncthreads();

    // phase 1: horizontal up-filter, 2 outputs (parities) per 6 reads.
    #pragma unroll
    for (int k = 0; k < 6; ++k) {
        int m = ty + 8 * k; if (m >= 42) break;
        #pragma unroll
        for (int j = 0; j < 2; ++j) {
            int h = tx + 32 * j; if (h >= 37) continue;
            float v[6];
            #pragma unroll
            for (int q = 0; q < 6; ++q) v[q] = It[m * 44 + h + 5 - q];
            float e = 0.f, o = 0.f;
            #pragma unroll
            for (int q = 0; q < 6; ++q) { e += cu[2 * q] * v[q]; o += cu[2 * q + 1] * v[q]; }
            *reinterpret_cast<float2*>(hu + m * 76 + 2 * h) = make_float2(2.f * e, 2.f * o);
        }
    }
    __syncthreads();

    // phase 2: vertical up-filter + lrelu*sqrt2 + clamp, sliding register
    // window down each column: thread (rx, seg) owns 13/13/11 row-pairs.
    {
        int rx  = tid % 74;
        int seg = tid / 74;              // 0..2 active; seg 3 (34 threads) idle
        if (seg < 3) {
            int r0  = seg * 13;
            int cnt = (seg == 2) ? 11 : 13;
            float wnd[6];
            #pragma unroll
            for (int i = 0; i < 5; ++i) wnd[i] = hu[(r0 + i) * 76 + rx];
            #pragma unroll
            for (int i = 0; i < 13; ++i) {
                if (i < cnt) {
                    wnd[5] = hu[(r0 + i + 5) * 76 + rx];
                    float e = 0.f, o = 0.f;
                    #pragma unroll
                    for (int q = 0; q < 6; ++q) {
                        e += cu[2 * q] * wnd[5 - q];
                        o += cu[2 * q + 1] * wnd[5 - q];
                    }
                    e *= 2.f; o *= 2.f;
                    e = (e >= 0.f ? e : e * 0.2f) * 1.4142135623730951f;
                    o = (o >= 0.f ? o : o * 0.2f) * 1.4142135623730951f;
                    e = fminf(fmaxf(e, -256.f), 256.f);
                    o = fminf(fmaxf(o, -256.f), 256.f);
                    int r = r0 + i;
                    zt[(2 * r) * 76 + rx]     = e;
                    zt[(2 * r + 1) * 76 + rx] = o;
                    #pragma unroll
                    for (int k2 = 0; k2 < 5; ++k2) wnd[k2] = wnd[k2 + 1];
                }
            }
        }
    }
    __syncthreads();

    // phase 3: down horizontal (+decimate x), 2 adjacent outputs per 7 float2 reads.
    #pragma unroll
    for (int k = 0; k < 5; ++k) {
        int ry = ty4 + 16 * k; if (ry >= 74) break;
        const float* zr = zt + ry * 76 + 4 * tx4;
        float z[14];
        #pragma unroll
        for (int t = 0; t < 7; ++t) {
            float2 p2 = *reinterpret_cast<const float2*>(zr + 2 * t);
            z[2 * t] = p2.x; z[2 * t + 1] = p2.y;
        }
        float a0 = 0.f, a1 = 0.f;
        #pragma unroll
        for (int u = 0; u < 12; ++u) { a0 += z[u] * cd[11 - u]; a1 += z[u + 2] * cd[11 - u]; }
        *reinterpret_cast<float2*>(dh + ry * 36 + 2 * tx4) = make_float2(a0, a1);
    }
    __syncthreads();

    // phase 4: down vertical (+decimate y) + store, 2 rows per 14 reads.
    #pragma unroll
    for (int k = 0; k < 2; ++k) {
        int r2 = ty + 8 * k;                 // oy pair = (2*r2, 2*r2+1)
        float d[14];
        #pragma unroll
        for (int v = 0; v < 14; ++v) d[v] = dh[(4 * r2 + v) * 36 + tx];
        float a0 = 0.f, a1 = 0.f;
        #pragma unroll
        for (int v = 0; v < 12; ++v) { a0 += d[v] * cd[11 - v]; a1 += d[v + 2] * cd[11 - v]; }
        float* op = out + (size_t)img * 64 * 64 + (oy0 + 2 * r2) * 64 + ox0 + tx;
        op[0]  = a0;
        op[64] = a1;
    }
}

extern "C" void kernel_launch(void* const* d_in, const int* in_sizes, int n_in,
                              void* d_out, int out_size, void* d_ws, size_t ws_size,
                              hipStream_t stream) {
    const float* x    = (const float*)d_in[0];
    const float* w    = (const float*)d_in[1];
    const float* aw   = (const float*)d_in[2];
    const float* ab   = (const float*)d_in[3];
    const float* cw   = (const float*)d_in[4];
    const float* bias = (const float*)d_in[5];
    const float* uf   = (const float*)d_in[6];
    const float* df   = (const float*)d_in[7];
    const float* ema  = (const float*)d_in[8];
    float* out = (float*)d_out;

    float* ws   = (float*)d_ws;
    float* s_   = ws;                                   // 4096
    float* coef = ws + 4096;                            // 4096
    float* r_   = ws + 8192;                            // 262144
    // bf16 regions (sizes in float-slots): y1 8,921,088 | xt 9,469,952 | wb 1,179,648
    __hip_bfloat16* y1 = (__hip_bfloat16*)(ws + 270336);
    __hip_bfloat16* xt = (__hip_bfloat16*)(ws + 270336 + 8921088);
    __hip_bfloat16* wb = (__hip_bfloat16*)(ws + 270336 + 8921088 + 9469952);

    k_style_s   <<<1024, 256, 0, stream>>>(w, aw, ab, s_);
    k_prep_w    <<<1024, 256, 0, stream>>>(cw, wb, r_);
    k_style_coef<<<1024, 256, 0, stream>>>(s_, r_, ema, coef);
    k_prep_x    <<<dim3(68, 8), 256, 0, stream>>>(x, s_, xt);
    k_conv_mfma <<<448, 512, 0, stream>>>(wb, xt, coef, bias, y1);
    k_style_fir <<<dim3(2, 2, 4096), 256, 0, stream>>>(y1, uf, df, out);
}

// Round 20
// 361.093 us; speedup vs baseline: 1.3415x; 1.3415x over previous
//
#include <hip/hip_runtime.h>
#include <hip/hip_bf16.h>

// StyleLayer: modulated conv3x3 as bf16 MFMA implicit GEMM (demod folded into
// input/output scales) + fused polyphase upfirdn(up2)->lrelu/clamp->upfirdn(down2).
// B=8, CIN=COUT=SDIM=512, H=W=64, K=3, taps=12, out 64x64. Conv out 66x66 (=4356 px).
// Round-20 = resubmit of round-18/19 (infra failures): exact revert to the best
// measured config (round-15, 361.3 us); r16/r17 160-px tiles regressed
// (r17 WRITE_SIZE 372 MB = acc spill at the 128-VGPR budget).

#define B_    8
#define CIN_  512
#define COUT_ 512
#define SDIM_ 512
#define H_    64
#define W_    64
#define HO_   66
#define NPIX  4356          // 66*66
#define XP    68            // padded input spatial (origin shift 2)

typedef short s8v  __attribute__((ext_vector_type(8)));   // 8 bf16 in 4 VGPRs
typedef float f4v  __attribute__((ext_vector_type(4)));

#define WAITV3() asm volatile("s_waitcnt vmcnt(3)" ::: "memory")
#define WAITV0() asm volatile("s_waitcnt vmcnt(0)" ::: "memory")

// ---------------- s[b,c] = w @ (aw/sqrt(SDIM)).T + ab ----------------
// one wave per output element; lane-strided coalesced loads + shuffle reduce.
__global__ __launch_bounds__(256) void k_style_s(
    const float* __restrict__ w, const float* __restrict__ aw,
    const float* __restrict__ ab, float* __restrict__ s) {
    const int t  = blockIdx.x * 4 + (threadIdx.x >> 6);   // 4096 outputs
    const int ln = threadIdx.x & 63;
    const int b = t >> 9, c = t & 511;
    const float* wp = w + b * SDIM_;
    const float* ap = aw + (size_t)c * SDIM_;
    float acc = 0.f;
    #pragma unroll
    for (int j = 0; j < 8; ++j) { int k = ln + 64 * j; acc += wp[k] * ap[k]; }
    #pragma unroll
    for (int off = 32; off; off >>= 1) acc += __shfl_down(acc, off, 64);
    if (ln == 0) s[t] = acc * 0.044194173824159216f + ab[c];
}

// ---------------- coef[b,o] = scale * rsqrt(sum_c s^2 r) * rsqrt(ema) ----------------
__global__ __launch_bounds__(256) void k_style_coef(
    const float* __restrict__ s, const float* __restrict__ r,
    const float* __restrict__ ema, float* __restrict__ coef) {
    const int t  = blockIdx.x * 4 + (threadIdx.x >> 6);   // 4096 outputs
    const int ln = threadIdx.x & 63;
    const int b = t >> 9, o = t & 511;
    const float* sp = s + b * 512;
    const float* rp = r + (size_t)o * 512;
    float acc = 0.f;
    #pragma unroll
    for (int j = 0; j < 8; ++j) {
        int k = ln + 64 * j;
        float sv = sp[k];
        acc += sv * sv * rp[k];
    }
    #pragma unroll
    for (int off = 32; off; off >>= 1) acc += __shfl_down(acc, off, 64);
    if (ln == 0) {
        float d  = rsqrtf(acc * (1.0f / 4608.0f) + 1e-8f);
        coef[t] = d * rsqrtf(ema[0]) * 0.014731391274719739f;
    }
}

// ---------------- wb[tap][o][c] = bf16(cw[o][c][tap]);  r[o*512+c] = sum_tap cw^2 ----
__global__ __launch_bounds__(256) void k_prep_w(const float* __restrict__ cw,
                                                __hip_bfloat16* __restrict__ wb,
                                                float* __restrict__ r) {
    __shared__ float sm[2304];
    const int base = blockIdx.x * 256;                // pair index o*512+c; 1024 blocks
    const int tid  = threadIdx.x;
    const float* src = cw + (size_t)base * 9;
    for (int i = tid; i < 2304; i += 256) sm[i] = src[i];
    __syncthreads();
    float a = 0.f;
    ushort u[9];
    #pragma unroll
    for (int k = 0; k < 9; ++k) {
        float v = sm[tid * 9 + k];                    // 2-way bank alias: free
        a += v * v;
        __hip_bfloat16 h = __float2bfloat16(v);
        u[k] = *reinterpret_cast<ushort*>(&h);
    }
    r[base + tid] = a;
    ushort* wbu = reinterpret_cast<ushort*>(wb);
    #pragma unroll
    for (int tap = 0; tap < 9; ++tap)
        wbu[tap * 262144 + base + tid] = u[tap];
}

// ---------------- xt[b][y][x][c] = bf16(x[b][c][y-2][x-2] * s[b][c]), zero pad ----
__global__ __launch_bounds__(256) void k_prep_x(const float* __restrict__ x,
                                                const float* __restrict__ s,
                                                __hip_bfloat16* __restrict__ xt) {
    __shared__ float tile[64][65];
    const int y = blockIdx.x;            // 0..67
    const int b = blockIdx.y;
    const int tid = threadIdx.x;
    const bool yin = (y >= 2 && y < 66);
    __hip_bfloat16* orow = xt + ((size_t)(b * XP + y)) * XP * 512;
    for (int c0 = 0; c0 < 512; c0 += 64) {
        if (yin) {
            for (int i = tid; i < 64 * 64; i += 256) {
                int c = i >> 6, xx = i & 63;
                tile[c][xx] = x[(((size_t)b * 512 + c0 + c) * 64 + (y - 2)) * 64 + xx]
                              * s[b * 512 + c0 + c];
            }
        }
        __syncthreads();
        for (int j = tid; j < 68 * 8; j += 256) {     // 68 x-positions, 8 c-groups of 8
            int xx = j >> 3, cg = j & 7;
            bool xin = yin && (xx >= 2 && xx < 66);
            union { ushort u[8]; float4 f4; } pk;
            #pragma unroll
            for (int k = 0; k < 8; ++k) {
                float v = xin ? tile[cg * 8 + k][xx - 2] : 0.f;
                __hip_bfloat16 h = __float2bfloat16(v);
                pk.u[k] = *reinterpret_cast<ushort*>(&h);
            }
            *reinterpret_cast<float4*>(orow + (size_t)xx * 512 + c0 + cg * 8) = pk.f4;
        }
        __syncthreads();
    }
}

// ---------------- MFMA implicit-GEMM conv ----------------
// 256 o x 128 px tile, 8 waves (512 thr), K = 9 taps x 512 c, BK=32.
// 3-buffer rotation, counted s_waitcnt vmcnt(3).
// Grid-quantization fix: 560 tiles on 512 blocks (2/CU exactly); the 48
// double-duty blocks are dispatched FIRST (6 per XCD) so their 2nd tile
// overlaps the main phase instead of trailing as a 48-block straggler round.
__device__ __forceinline__ void gload16u(const char* base, unsigned voff, void* l) {
    __builtin_amdgcn_global_load_lds(
        (const __attribute__((address_space(1))) unsigned*)(base + voff),
        (__attribute__((address_space(3))) unsigned*)l, 16, 0, 0);
}

__global__ __launch_bounds__(512) void k_conv_mfma(
    const __hip_bfloat16* __restrict__ wb, const __hip_bfloat16* __restrict__ xt,
    const float* __restrict__ coef, const float* __restrict__ bias,
    __hip_bfloat16* __restrict__ y1)
{
    __shared__ __hip_bfloat16 lds[3][12288];          // [buf][A(8192) | B(4096)]

    // block -> (xcd, j): bid<48 are double-duty (j 0..5), dispatched first.
    const int bid   = blockIdx.x;                     // 512 blocks
    const int dbl   = bid < 48;
    const int rr2   = dbl ? bid : bid - 48;
    const int xcd   = rr2 & 7;
    const int j     = dbl ? (rr2 >> 3) : (6 + (rr2 >> 3));   // 0..63 per XCD
    const int ntile = dbl ? 2 : 1;

    const int tid = threadIdx.x, wv = tid >> 6, ln = tid & 63;
    const int wm = wv >> 1, wn = wv & 1;              // 4 o-quadrants x 2 px-halves

    // ---- tile-invariant per-lane constants ----
    const int srow = tid >> 2, ssl = tid & 3;         // staging row 0..127, 16B slot
    const unsigned swzs = (unsigned)((ssl ^ ((srow >> 1) & 3)) << 3);
    int aoff[4], boff[4];
    #pragma unroll
    for (int f = 0; f < 4; ++f) {
        int r  = wm * 64 + f * 16 + (ln & 15);
        aoff[f] = (r * 32 + (((ln >> 4) ^ ((r >> 1) & 3)) << 3)) * 2;
        int rb = wn * 64 + f * 16 + (ln & 15);
        boff[f] = (8192 + rb * 32 + (((ln >> 4) ^ ((rb >> 1) & 3)) << 3)) * 2;
    }
    const char* wbB = (const char*)wb;

    for (int tt = 0; tt < ntile; ++tt) {
        const int pos  = (tt == 0) ? j : (64 + j);    // 0..69 within XCD range
        const int flat = xcd * 70 + pos;              // 0..559, bijective
        const int pi = flat % 35;
        const int t2 = flat / 35;                     // 0..15: (oi*8 + b)
        const int b  = t2 & 7;
        const int o0 = (t2 >> 3) * 256;
        const int p0 = pi * 128;

        // ---- per-tile staging offsets ----
        const char* xtB = (const char*)(xt + (size_t)b * XP * XP * 512);
        unsigned voffA0 = ((unsigned)(o0 + srow) * 512u + swzs) * 2u;
        unsigned voffA1 = ((unsigned)(o0 + 128 + srow) * 512u + swzs) * 2u;
        unsigned voffB0;
        {
            int p = p0 + srow; if (p > NPIX - 1) p = NPIX - 1;
            int py = (int)(((unsigned)p * 63551u) >> 22); // p/66
            int px = p - py * 66;
            voffB0 = ((unsigned)(py * XP + px) * 512u + swzs) * 2u;
        }

        f4v acc[4][4];
        #pragma unroll
        for (int fm = 0; fm < 4; ++fm)
            #pragma unroll
            for (int fn = 0; fn < 4; ++fn) acc[fm][fn] = (f4v){0.f, 0.f, 0.f, 0.f};

        auto stage = [&](int st, int buf) {           // buf is a literal at call sites
            int tap = st >> 4;                        // uniform -> SALU
            int ki  = (tap * 11) >> 5;                // tap/3 for tap<9
            int kj  = tap - ki * 3;
            unsigned ccb  = (unsigned)(st & 15) << 6; // c-chunk bytes
            unsigned offA = (unsigned)tap * 524288u + ccb;            // tap*512*512*2B
            unsigned offB = (unsigned)(ki * XP + kj) * 1024u + ccb;   // (ki*XP+kj)*512*2B
            __hip_bfloat16* dst = &lds[buf][0] + wv * 512;
            gload16u(wbB, voffA0 + offA, dst);        // A rows   0..127
            gload16u(wbB, voffA1 + offA, dst + 4096); // A rows 128..255
            gload16u(xtB, voffB0 + offB, dst + 8192); // B rows   0..127
        };

        auto compute = [&](int buf) {                 // buf literal -> const LDS bases
            const char* base = (const char*)&lds[buf][0];
            s8v af[4], bfv[4];
            #pragma unroll
            for (int f = 0; f < 4; ++f) {
                af[f]  = *reinterpret_cast<const s8v*>(base + aoff[f]);
                bfv[f] = *reinterpret_cast<const s8v*>(base + boff[f]);
            }
            #pragma unroll
            for (int fm = 0; fm < 4; ++fm)
                #pragma unroll
                for (int fn = 0; fn < 4; ++fn)
                    acc[fm][fn] = __builtin_amdgcn_mfma_f32_16x16x32_bf16(
                        af[fm], bfv[fn], acc[fm][fn], 0, 0, 0);
        };

        stage(0, 0);
        stage(1, 1);

        // steps 0..140 in groups of 3; counted vmcnt(3) keeps the next step's
        // 3 loads in flight across every barrier.
        #pragma unroll 1
        for (int st = 0; st < 141; st += 3) {
            WAITV3(); __builtin_amdgcn_s_barrier();
            compute(0); stage(st + 2, 2);
            WAITV3(); __builtin_amdgcn_s_barrier();
            compute(1); stage(st + 3, 0);
            WAITV3(); __builtin_amdgcn_s_barrier();
            compute(2); stage(st + 4, 1);
        }
        // epilogue: steps 141 (buf0), 142 (buf1), 143 (buf2; staged here).
        WAITV3(); __builtin_amdgcn_s_barrier();
        stage(143, 2); compute(0);
        WAITV3(); __builtin_amdgcn_s_barrier();
        compute(1);
        WAITV0(); __builtin_amdgcn_s_barrier();
        compute(2);

        // C-write: y1[b][o][p] bf16 = acc*coef + bias
        #pragma unroll
        for (int fm = 0; fm < 4; ++fm) {
            #pragma unroll
            for (int fn = 0; fn < 4; ++fn) {
                int p = p0 + wn * 64 + fn * 16 + (ln & 15);
                if (p < NPIX) {
                    int ob = o0 + wm * 64 + fm * 16 + (ln >> 4) * 4;
                    #pragma unroll
                    for (int jj = 0; jj < 4; ++jj) {
                        int o = ob + jj;
                        float v = acc[fm][fn][jj] * coef[b * 512 + o] + bias[o];
                        y1[((size_t)(b * 512 + o)) * NPIX + p] = __float2bfloat16(v);
                    }
                }
            }
        }
    }
}

// ---------------- fused upfirdn2(up2,pad(9,8)) -> lrelu*sqrt2,clamp -> upfirdn2(down2) ----
// 32x32 output tile. No integer div/mod in hot loops; polyphase even/odd pair
// sharing; phase-2 uses a per-column sliding register window (1 new LDS read
// per output row-pair, was 6); It/zt and hu/dh share LDS regions.
__global__ __launch_bounds__(256) void k_style_fir(
    const __hip_bfloat16* __restrict__ y1, const float* __restrict__ uf,
    const float* __restrict__ df, float* __restrict__ out)
{
    __shared__ float smA[5632];          // It[42][44] then zt[74][76]
    __shared__ float smB[3200];          // hu[42][76] then dh[74][36]
    float* It = smA;                     // stride 44
    float* hu = smB;                     // stride 76
    float* zt = smA;                     // stride 76
    float* dh = smB;                     // stride 36

    const int img = blockIdx.z;          // b*COUT + o
    const int oy0 = blockIdx.y * 32;
    const int ox0 = blockIdx.x * 32;
    const int tid = threadIdx.x;
    const __hip_bfloat16* I = y1 + (size_t)img * NPIX;

    float cu[12], cd[12];
    #pragma unroll
    for (int q = 0; q < 12; ++q) { cu[q] = uf[q]; cd[q] = df[q]; }

    const int ty = tid >> 5, tx = tid & 31;   // 8 x 32
    const int ty4 = tid >> 4, tx4 = tid & 15; // 16 x 16

    // phase 0: load It[42][42] <- y1 tile rows/cols [oy0-4, oy0+37]
    #pragma unroll
    for (int k = 0; k < 6; ++k) {
        int rr = ty + 8 * k; if (rr >= 42) break;
        int gy = oy0 - 4 + rr;
        bool yin = (gy >= 0 && gy < HO_);
        #pragma unroll
        for (int j = 0; j < 2; ++j) {
            int cc = tx + 32 * j; if (cc >= 42) continue;
            int gx = ox0 - 4 + cc;
            float v = 0.f;
            if (yin && gx >= 0 && gx < HO_) v = __bfloat162float(I[gy * HO_ + gx]);
            It[rr * 44 + cc] = v;
        }
    }
    __syncthreads();

    // phase 1: horizontal up-filter, 2 outputs (parities) per 6 reads.
    #pragma unroll
    for (int k = 0; k < 6; ++k) {
        int m = ty + 8 * k; if (m >= 42) break;
        #pragma unroll
        for (int j = 0; j < 2; ++j) {
            int h = tx + 32 * j; if (h >= 37) continue;
            float v[6];
            #pragma unroll
            for (int q = 0; q < 6; ++q) v[q] = It[m * 44 + h + 5 - q];
            float e = 0.f, o = 0.f;
            #pragma unroll
            for (int q = 0; q < 6; ++q) { e += cu[2 * q] * v[q]; o += cu[2 * q + 1] * v[q]; }
            *reinterpret_cast<float2*>(hu + m * 76 + 2 * h) = make_float2(2.f * e, 2.f * o);
        }
    }
    __syncthreads();

    // phase 2: vertical up-filter + lrelu*sqrt2 + clamp, sliding register
    // window down each column: thread (rx, seg) owns 13/13/11 row-pairs.
    {
        int rx  = tid % 74;
        int seg = tid / 74;              // 0..2 active; seg 3 (34 threads) idle
        if (seg < 3) {
            int r0  = seg * 13;
            int cnt = (seg == 2) ? 11 : 13;
            float wnd[6];
            #pragma unroll
            for (int i = 0; i < 5; ++i) wnd[i] = hu[(r0 + i) * 76 + rx];
            #pragma unroll
            for (int i = 0; i < 13; ++i) {
                if (i < cnt) {
                    wnd[5] = hu[(r0 + i + 5) * 76 + rx];
                    float e = 0.f, o = 0.f;
                    #pragma unroll
                    for (int q = 0; q < 6; ++q) {
                        e += cu[2 * q] * wnd[5 - q];
                        o += cu[2 * q + 1] * wnd[5 - q];
                    }
                    e *= 2.f; o *= 2.f;
                    e = (e >= 0.f ? e : e * 0.2f) * 1.4142135623730951f;
                    o = (o >= 0.f ? o : o * 0.2f) * 1.4142135623730951f;
                    e = fminf(fmaxf(e, -256.f), 256.f);
                    o = fminf(fmaxf(o, -256.f), 256.f);
                    int r = r0 + i;
                    zt[(2 * r) * 76 + rx]     = e;
                    zt[(2 * r + 1) * 76 + rx] = o;
                    #pragma unroll
                    for (int k2 = 0; k2 < 5; ++k2) wnd[k2] = wnd[k2 + 1];
                }
            }
        }
    }
    __syncthreads();

    // phase 3: down horizontal (+decimate x), 2 adjacent outputs per 7 float2 reads.
    #pragma unroll
    for (int k = 0; k < 5; ++k) {
        int ry = ty4 + 16 * k; if (ry >= 74) break;
        const float* zr = zt + ry * 76 + 4 * tx4;
        float z[14];
        #pragma unroll
        for (int t = 0; t < 7; ++t) {
            float2 p2 = *reinterpret_cast<const float2*>(zr + 2 * t);
            z[2 * t] = p2.x; z[2 * t + 1] = p2.y;
        }
        float a0 = 0.f, a1 = 0.f;
        #pragma unroll
        for (int u = 0; u < 12; ++u) { a0 += z[u] * cd[11 - u]; a1 += z[u + 2] * cd[11 - u]; }
        *reinterpret_cast<float2*>(dh + ry * 36 + 2 * tx4) = make_float2(a0, a1);
    }
    __syncthreads();

    // phase 4: down vertical (+decimate y) + store, 2 rows per 14 reads.
    #pragma unroll
    for (int k = 0; k < 2; ++k) {
        int r2 = ty + 8 * k;                 // oy pair = (2*r2, 2*r2+1)
        float d[14];
        #pragma unroll
        for (int v = 0; v < 14; ++v) d[v] = dh[(4 * r2 + v) * 36 + tx];
        float a0 = 0.f, a1 = 0.f;
        #pragma unroll
        for (int v = 0; v < 12; ++v) { a0 += d[v] * cd[11 - v]; a1 += d[v + 2] * cd[11 - v]; }
        float* op = out + (size_t)img * 64 * 64 + (oy0 + 2 * r2) * 64 + ox0 + tx;
        op[0]  = a0;
        op[64] = a1;
    }
}

extern "C" void kernel_launch(void* const* d_in, const int* in_sizes, int n_in,
                              void* d_out, int out_size, void* d_ws, size_t ws_size,
                              hipStream_t stream) {
    const float* x    = (const float*)d_in[0];
    const float* w    = (const float*)d_in[1];
    const float* aw   = (const float*)d_in[2];
    const float* ab   = (const float*)d_in[3];
    const float* cw   = (const float*)d_in[4];
    const float* bias = (const float*)d_in[5];
    const float* uf   = (const float*)d_in[6];
    const float* df   = (const float*)d_in[7];
    const float* ema  = (const float*)d_in[8];
    float* out = (float*)d_out;

    float* ws   = (float*)d_ws;
    float* s_   = ws;                                   // 4096
    float* coef = ws + 4096;                            // 4096
    float* r_   = ws + 8192;                            // 262144
    // bf16 regions (sizes in float-slots): y1 8,921,088 | xt 9,469,952 | wb 1,179,648
    __hip_bfloat16* y1 = (__hip_bfloat16*)(ws + 270336);
    __hip_bfloat16* xt = (__hip_bfloat16*)(ws + 270336 + 8921088);
    __hip_bfloat16* wb = (__hip_bfloat16*)(ws + 270336 + 8921088 + 9469952);

    k_style_s   <<<1024, 256, 0, stream>>>(w, aw, ab, s_);
    k_prep_w    <<<1024, 256, 0, stream>>>(cw, wb, r_);
    k_style_coef<<<1024, 256, 0, stream>>>(s_, r_, ema, coef);
    k_prep_x    <<<dim3(68, 8), 256, 0, stream>>>(x, s_, xt);
    k_conv_mfma <<<512, 512, 0, stream>>>(wb, xt, coef, bias, y1);
    k_style_fir <<<dim3(2, 2, 4096), 256, 0, stream>>>(y1, uf, df, out);
}

// Round 21
// 354.808 us; speedup vs baseline: 1.3652x; 1.0177x over previous
//
#include <hip/hip_runtime.h>
#include <hip/hip_bf16.h>

// StyleLayer: modulated conv3x3 as bf16 MFMA implicit GEMM (demod folded into
// input/output scales) + fused polyphase upfirdn(up2)->lrelu/clamp->upfirdn(down2).
// B=8, CIN=COUT=SDIM=512, H=W=64, K=3, taps=12, out 64x64. Conv out 66x66 (=4356 px).
// Round-21: conv/preps identical to round-20 (reproduced 361.1 us baseline);
// fir moves 256 -> 512 threads/block (same LDS, same per-output arithmetic):
// half the serial phase depth, occupancy 16 -> 32 waves/CU.

#define B_    8
#define CIN_  512
#define COUT_ 512
#define SDIM_ 512
#define H_    64
#define W_    64
#define HO_   66
#define NPIX  4356          // 66*66
#define XP    68            // padded input spatial (origin shift 2)

typedef short s8v  __attribute__((ext_vector_type(8)));   // 8 bf16 in 4 VGPRs
typedef float f4v  __attribute__((ext_vector_type(4)));

#define WAITV3() asm volatile("s_waitcnt vmcnt(3)" ::: "memory")
#define WAITV0() asm volatile("s_waitcnt vmcnt(0)" ::: "memory")

// ---------------- s[b,c] = w @ (aw/sqrt(SDIM)).T + ab ----------------
// one wave per output element; lane-strided coalesced loads + shuffle reduce.
__global__ __launch_bounds__(256) void k_style_s(
    const float* __restrict__ w, const float* __restrict__ aw,
    const float* __restrict__ ab, float* __restrict__ s) {
    const int t  = blockIdx.x * 4 + (threadIdx.x >> 6);   // 4096 outputs
    const int ln = threadIdx.x & 63;
    const int b = t >> 9, c = t & 511;
    const float* wp = w + b * SDIM_;
    const float* ap = aw + (size_t)c * SDIM_;
    float acc = 0.f;
    #pragma unroll
    for (int j = 0; j < 8; ++j) { int k = ln + 64 * j; acc += wp[k] * ap[k]; }
    #pragma unroll
    for (int off = 32; off; off >>= 1) acc += __shfl_down(acc, off, 64);
    if (ln == 0) s[t] = acc * 0.044194173824159216f + ab[c];
}

// ---------------- coef[b,o] = scale * rsqrt(sum_c s^2 r) * rsqrt(ema) ----------------
__global__ __launch_bounds__(256) void k_style_coef(
    const float* __restrict__ s, const float* __restrict__ r,
    const float* __restrict__ ema, float* __restrict__ coef) {
    const int t  = blockIdx.x * 4 + (threadIdx.x >> 6);   // 4096 outputs
    const int ln = threadIdx.x & 63;
    const int b = t >> 9, o = t & 511;
    const float* sp = s + b * 512;
    const float* rp = r + (size_t)o * 512;
    float acc = 0.f;
    #pragma unroll
    for (int j = 0; j < 8; ++j) {
        int k = ln + 64 * j;
        float sv = sp[k];
        acc += sv * sv * rp[k];
    }
    #pragma unroll
    for (int off = 32; off; off >>= 1) acc += __shfl_down(acc, off, 64);
    if (ln == 0) {
        float d  = rsqrtf(acc * (1.0f / 4608.0f) + 1e-8f);
        coef[t] = d * rsqrtf(ema[0]) * 0.014731391274719739f;
    }
}

// ---------------- wb[tap][o][c] = bf16(cw[o][c][tap]);  r[o*512+c] = sum_tap cw^2 ----
__global__ __launch_bounds__(256) void k_prep_w(const float* __restrict__ cw,
                                                __hip_bfloat16* __restrict__ wb,
                                                float* __restrict__ r) {
    __shared__ float sm[2304];
    const int base = blockIdx.x * 256;                // pair index o*512+c; 1024 blocks
    const int tid  = threadIdx.x;
    const float* src = cw + (size_t)base * 9;
    for (int i = tid; i < 2304; i += 256) sm[i] = src[i];
    __syncthreads();
    float a = 0.f;
    ushort u[9];
    #pragma unroll
    for (int k = 0; k < 9; ++k) {
        float v = sm[tid * 9 + k];                    // 2-way bank alias: free
        a += v * v;
        __hip_bfloat16 h = __float2bfloat16(v);
        u[k] = *reinterpret_cast<ushort*>(&h);
    }
    r[base + tid] = a;
    ushort* wbu = reinterpret_cast<ushort*>(wb);
    #pragma unroll
    for (int tap = 0; tap < 9; ++tap)
        wbu[tap * 262144 + base + tid] = u[tap];
}

// ---------------- xt[b][y][x][c] = bf16(x[b][c][y-2][x-2] * s[b][c]), zero pad ----
__global__ __launch_bounds__(256) void k_prep_x(const float* __restrict__ x,
                                                const float* __restrict__ s,
                                                __hip_bfloat16* __restrict__ xt) {
    __shared__ float tile[64][65];
    const int y = blockIdx.x;            // 0..67
    const int b = blockIdx.y;
    const int tid = threadIdx.x;
    const bool yin = (y >= 2 && y < 66);
    __hip_bfloat16* orow = xt + ((size_t)(b * XP + y)) * XP * 512;
    for (int c0 = 0; c0 < 512; c0 += 64) {
        if (yin) {
            for (int i = tid; i < 64 * 64; i += 256) {
                int c = i >> 6, xx = i & 63;
                tile[c][xx] = x[(((size_t)b * 512 + c0 + c) * 64 + (y - 2)) * 64 + xx]
                              * s[b * 512 + c0 + c];
            }
        }
        __syncthreads();
        for (int j = tid; j < 68 * 8; j += 256) {     // 68 x-positions, 8 c-groups of 8
            int xx = j >> 3, cg = j & 7;
            bool xin = yin && (xx >= 2 && xx < 66);
            union { ushort u[8]; float4 f4; } pk;
            #pragma unroll
            for (int k = 0; k < 8; ++k) {
                float v = xin ? tile[cg * 8 + k][xx - 2] : 0.f;
                __hip_bfloat16 h = __float2bfloat16(v);
                pk.u[k] = *reinterpret_cast<ushort*>(&h);
            }
            *reinterpret_cast<float4*>(orow + (size_t)xx * 512 + c0 + cg * 8) = pk.f4;
        }
        __syncthreads();
    }
}

// ---------------- MFMA implicit-GEMM conv ----------------
// 256 o x 128 px tile, 8 waves (512 thr), K = 9 taps x 512 c, BK=32.
// 3-buffer rotation, counted s_waitcnt vmcnt(3).
// Grid-quantization fix: 560 tiles on 512 blocks (2/CU exactly); the 48
// double-duty blocks are dispatched FIRST (6 per XCD) so their 2nd tile
// overlaps the main phase instead of trailing as a 48-block straggler round.
__device__ __forceinline__ void gload16u(const char* base, unsigned voff, void* l) {
    __builtin_amdgcn_global_load_lds(
        (const __attribute__((address_space(1))) unsigned*)(base + voff),
        (__attribute__((address_space(3))) unsigned*)l, 16, 0, 0);
}

__global__ __launch_bounds__(512) void k_conv_mfma(
    const __hip_bfloat16* __restrict__ wb, const __hip_bfloat16* __restrict__ xt,
    const float* __restrict__ coef, const float* __restrict__ bias,
    __hip_bfloat16* __restrict__ y1)
{
    __shared__ __hip_bfloat16 lds[3][12288];          // [buf][A(8192) | B(4096)]

    // block -> (xcd, j): bid<48 are double-duty (j 0..5), dispatched first.
    const int bid   = blockIdx.x;                     // 512 blocks
    const int dbl   = bid < 48;
    const int rr2   = dbl ? bid : bid - 48;
    const int xcd   = rr2 & 7;
    const int j     = dbl ? (rr2 >> 3) : (6 + (rr2 >> 3));   // 0..63 per XCD
    const int ntile = dbl ? 2 : 1;

    const int tid = threadIdx.x, wv = tid >> 6, ln = tid & 63;
    const int wm = wv >> 1, wn = wv & 1;              // 4 o-quadrants x 2 px-halves

    // ---- tile-invariant per-lane constants ----
    const int srow = tid >> 2, ssl = tid & 3;         // staging row 0..127, 16B slot
    const unsigned swzs = (unsigned)((ssl ^ ((srow >> 1) & 3)) << 3);
    int aoff[4], boff[4];
    #pragma unroll
    for (int f = 0; f < 4; ++f) {
        int r  = wm * 64 + f * 16 + (ln & 15);
        aoff[f] = (r * 32 + (((ln >> 4) ^ ((r >> 1) & 3)) << 3)) * 2;
        int rb = wn * 64 + f * 16 + (ln & 15);
        boff[f] = (8192 + rb * 32 + (((ln >> 4) ^ ((rb >> 1) & 3)) << 3)) * 2;
    }
    const char* wbB = (const char*)wb;

    for (int tt = 0; tt < ntile; ++tt) {
        const int pos  = (tt == 0) ? j : (64 + j);    // 0..69 within XCD range
        const int flat = xcd * 70 + pos;              // 0..559, bijective
        const int pi = flat % 35;
        const int t2 = flat / 35;                     // 0..15: (oi*8 + b)
        const int b  = t2 & 7;
        const int o0 = (t2 >> 3) * 256;
        const int p0 = pi * 128;

        // ---- per-tile staging offsets ----
        const char* xtB = (const char*)(xt + (size_t)b * XP * XP * 512);
        unsigned voffA0 = ((unsigned)(o0 + srow) * 512u + swzs) * 2u;
        unsigned voffA1 = ((unsigned)(o0 + 128 + srow) * 512u + swzs) * 2u;
        unsigned voffB0;
        {
            int p = p0 + srow; if (p > NPIX - 1) p = NPIX - 1;
            int py = (int)(((unsigned)p * 63551u) >> 22); // p/66
            int px = p - py * 66;
            voffB0 = ((unsigned)(py * XP + px) * 512u + swzs) * 2u;
        }

        f4v acc[4][4];
        #pragma unroll
        for (int fm = 0; fm < 4; ++fm)
            #pragma unroll
            for (int fn = 0; fn < 4; ++fn) acc[fm][fn] = (f4v){0.f, 0.f, 0.f, 0.f};

        auto stage = [&](int st, int buf) {           // buf is a literal at call sites
            int tap = st >> 4;                        // uniform -> SALU
            int ki  = (tap * 11) >> 5;                // tap/3 for tap<9
            int kj  = tap - ki * 3;
            unsigned ccb  = (unsigned)(st & 15) << 6; // c-chunk bytes
            unsigned offA = (unsigned)tap * 524288u + ccb;            // tap*512*512*2B
            unsigned offB = (unsigned)(ki * XP + kj) * 1024u + ccb;   // (ki*XP+kj)*512*2B
            __hip_bfloat16* dst = &lds[buf][0] + wv * 512;
            gload16u(wbB, voffA0 + offA, dst);        // A rows   0..127
            gload16u(wbB, voffA1 + offA, dst + 4096); // A rows 128..255
            gload16u(xtB, voffB0 + offB, dst + 8192); // B rows   0..127
        };

        auto compute = [&](int buf) {                 // buf literal -> const LDS bases
            const char* base = (const char*)&lds[buf][0];
            s8v af[4], bfv[4];
            #pragma unroll
            for (int f = 0; f < 4; ++f) {
                af[f]  = *reinterpret_cast<const s8v*>(base + aoff[f]);
                bfv[f] = *reinterpret_cast<const s8v*>(base + boff[f]);
            }
            #pragma unroll
            for (int fm = 0; fm < 4; ++fm)
                #pragma unroll
                for (int fn = 0; fn < 4; ++fn)
                    acc[fm][fn] = __builtin_amdgcn_mfma_f32_16x16x32_bf16(
                        af[fm], bfv[fn], acc[fm][fn], 0, 0, 0);
        };

        stage(0, 0);
        stage(1, 1);

        // steps 0..140 in groups of 3; counted vmcnt(3) keeps the next step's
        // 3 loads in flight across every barrier.
        #pragma unroll 1
        for (int st = 0; st < 141; st += 3) {
            WAITV3(); __builtin_amdgcn_s_barrier();
            compute(0); stage(st + 2, 2);
            WAITV3(); __builtin_amdgcn_s_barrier();
            compute(1); stage(st + 3, 0);
            WAITV3(); __builtin_amdgcn_s_barrier();
            compute(2); stage(st + 4, 1);
        }
        // epilogue: steps 141 (buf0), 142 (buf1), 143 (buf2; staged here).
        WAITV3(); __builtin_amdgcn_s_barrier();
        stage(143, 2); compute(0);
        WAITV3(); __builtin_amdgcn_s_barrier();
        compute(1);
        WAITV0(); __builtin_amdgcn_s_barrier();
        compute(2);

        // C-write: y1[b][o][p] bf16 = acc*coef + bias
        #pragma unroll
        for (int fm = 0; fm < 4; ++fm) {
            #pragma unroll
            for (int fn = 0; fn < 4; ++fn) {
                int p = p0 + wn * 64 + fn * 16 + (ln & 15);
                if (p < NPIX) {
                    int ob = o0 + wm * 64 + fm * 16 + (ln >> 4) * 4;
                    #pragma unroll
                    for (int jj = 0; jj < 4; ++jj) {
                        int o = ob + jj;
                        float v = acc[fm][fn][jj] * coef[b * 512 + o] + bias[o];
                        y1[((size_t)(b * 512 + o)) * NPIX + p] = __float2bfloat16(v);
                    }
                }
            }
        }
    }
}

// ---------------- fused upfirdn2(up2,pad(9,8)) -> lrelu*sqrt2,clamp -> upfirdn2(down2) ----
// 32x32 output tile, 512 threads (was 256): same LDS (35.3 KB -> 4 blocks/CU,
// now 32 waves/CU), per-phase serial depth halved. Identical per-output FMA
// order -> bit-identical results.
__global__ __launch_bounds__(512) void k_style_fir(
    const __hip_bfloat16* __restrict__ y1, const float* __restrict__ uf,
    const float* __restrict__ df, float* __restrict__ out)
{
    __shared__ float smA[5632];          // It[42][44] then zt[74][76]
    __shared__ float smB[3200];          // hu[42][76] then dh[74][36]
    float* It = smA;                     // stride 44
    float* hu = smB;                     // stride 76
    float* zt = smA;                     // stride 76
    float* dh = smB;                     // stride 36

    const int img = blockIdx.z;          // b*COUT + o
    const int oy0 = blockIdx.y * 32;
    const int ox0 = blockIdx.x * 32;
    const int tid = threadIdx.x;
    const __hip_bfloat16* I = y1 + (size_t)img * NPIX;

    float cu[12], cd[12];
    #pragma unroll
    for (int q = 0; q < 12; ++q) { cu[q] = uf[q]; cd[q] = df[q]; }

    const int ty16 = tid >> 5, tx = tid & 31;   // 16 x 32
    const int ty32 = tid >> 4, tx4 = tid & 15;  // 32 x 16

    // phase 0: load It[42][42] <- y1 tile rows/cols [oy0-4, oy0+37]
    #pragma unroll
    for (int k = 0; k < 3; ++k) {
        int rr = ty16 + 16 * k; if (rr >= 42) break;
        int gy = oy0 - 4 + rr;
        bool yin = (gy >= 0 && gy < HO_);
        #pragma unroll
        for (int j = 0; j < 2; ++j) {
            int cc = tx + 32 * j; if (cc >= 42) continue;
            int gx = ox0 - 4 + cc;
            float v = 0.f;
            if (yin && gx >= 0 && gx < HO_) v = __bfloat162float(I[gy * HO_ + gx]);
            It[rr * 44 + cc] = v;
        }
    }
    __syncthreads();

    // phase 1: horizontal up-filter, 2 outputs (parities) per 6 reads.
    #pragma unroll
    for (int k = 0; k < 3; ++k) {
        int m = ty16 + 16 * k; if (m >= 42) break;
        #pragma unroll
        for (int j = 0; j < 2; ++j) {
            int h = tx + 32 * j; if (h >= 37) continue;
            float v[6];
            #pragma unroll
            for (int q = 0; q < 6; ++q) v[q] = It[m * 44 + h + 5 - q];
            float e = 0.f, o = 0.f;
            #pragma unroll
            for (int q = 0; q < 6; ++q) { e += cu[2 * q] * v[q]; o += cu[2 * q + 1] * v[q]; }
            *reinterpret_cast<float2*>(hu + m * 76 + 2 * h) = make_float2(2.f * e, 2.f * o);
        }
    }
    __syncthreads();

    // phase 2: vertical up-filter + lrelu*sqrt2 + clamp, sliding register
    // window down each column: 6 segments x 74 columns (7/6/6/6/6/6 row-pairs).
    {
        int rx  = tid % 74;
        int seg = tid / 74;              // 0..5 active; 68 threads idle
        if (seg < 6) {
            int r0  = (seg == 0) ? 0 : (1 + seg * 6);
            int cnt = (seg == 0) ? 7 : 6;
            float wnd[6];
            #pragma unroll
            for (int i = 0; i < 5; ++i) wnd[i] = hu[(r0 + i) * 76 + rx];
            #pragma unroll
            for (int i = 0; i < 7; ++i) {
                if (i < cnt) {
                    wnd[5] = hu[(r0 + i + 5) * 76 + rx];
                    float e = 0.f, o = 0.f;
                    #pragma unroll
                    for (int q = 0; q < 6; ++q) {
                        e += cu[2 * q] * wnd[5 - q];
                        o += cu[2 * q + 1] * wnd[5 - q];
                    }
                    e *= 2.f; o *= 2.f;
                    e = (e >= 0.f ? e : e * 0.2f) * 1.4142135623730951f;
                    o = (o >= 0.f ? o : o * 0.2f) * 1.4142135623730951f;
                    e = fminf(fmaxf(e, -256.f), 256.f);
                    o = fminf(fmaxf(o, -256.f), 256.f);
                    int r = r0 + i;
                    zt[(2 * r) * 76 + rx]     = e;
                    zt[(2 * r + 1) * 76 + rx] = o;
                    #pragma unroll
                    for (int k2 = 0; k2 < 5; ++k2) wnd[k2] = wnd[k2 + 1];
                }
            }
        }
    }
    __syncthreads();

    // phase 3: down horizontal (+decimate x), 2 adjacent outputs per 7 float2 reads.
    #pragma unroll
    for (int k = 0; k < 3; ++k) {
        int ry = ty32 + 32 * k; if (ry >= 74) break;
        const float* zr = zt + ry * 76 + 4 * tx4;
        float z[14];
        #pragma unroll
        for (int t = 0; t < 7; ++t) {
            float2 p2 = *reinterpret_cast<const float2*>(zr + 2 * t);
            z[2 * t] = p2.x; z[2 * t + 1] = p2.y;
        }
        float a0 = 0.f, a1 = 0.f;
        #pragma unroll
        for (int u = 0; u < 12; ++u) { a0 += z[u] * cd[11 - u]; a1 += z[u + 2] * cd[11 - u]; }
        *reinterpret_cast<float2*>(dh + ry * 36 + 2 * tx4) = make_float2(a0, a1);
    }
    __syncthreads();

    // phase 4: down vertical (+decimate y) + store, one row-pair per thread.
    {
        int r2 = ty16;                       // pair 0..15 -> oy rows (2r2, 2r2+1)
        float d[14];
        #pragma unroll
        for (int v = 0; v < 14; ++v) d[v] = dh[(4 * r2 + v) * 36 + tx];
        float a0 = 0.f, a1 = 0.f;
        #pragma unroll
        for (int v = 0; v < 12; ++v) { a0 += d[v] * cd[11 - v]; a1 += d[v + 2] * cd[11 - v]; }
        float* op = out + (size_t)img * 64 * 64 + (oy0 + 2 * r2) * 64 + ox0 + tx;
        op[0]  = a0;
        op[64] = a1;
    }
}

extern "C" void kernel_launch(void* const* d_in, const int* in_sizes, int n_in,
                              void* d_out, int out_size, void* d_ws, size_t ws_size,
                              hipStream_t stream) {
    const float* x    = (const float*)d_in[0];
    const float* w    = (const float*)d_in[1];
    const float* aw   = (const float*)d_in[2];
    const float* ab   = (const float*)d_in[3];
    const float* cw   = (const float*)d_in[4];
    const float* bias = (const float*)d_in[5];
    const float* uf   = (const float*)d_in[6];
    const float* df   = (const float*)d_in[7];
    const float* ema  = (const float*)d_in[8];
    float* out = (float*)d_out;

    float* ws   = (float*)d_ws;
    float* s_   = ws;                                   // 4096
    float* coef = ws + 4096;                            // 4096
    float* r_   = ws + 8192;                            // 262144
    // bf16 regions (sizes in float-slots): y1 8,921,088 | xt 9,469,952 | wb 1,179,648
    __hip_bfloat16* y1 = (__hip_bfloat16*)(ws + 270336);
    __hip_bfloat16* xt = (__hip_bfloat16*)(ws + 270336 + 8921088);
    __hip_bfloat16* wb = (__hip_bfloat16*)(ws + 270336 + 8921088 + 9469952);

    k_style_s   <<<1024, 256, 0, stream>>>(w, aw, ab, s_);
    k_prep_w    <<<1024, 256, 0, stream>>>(cw, wb, r_);
    k_style_coef<<<1024, 256, 0, stream>>>(s_, r_, ema, coef);
    k_prep_x    <<<dim3(68, 8), 256, 0, stream>>>(x, s_, xt);
    k_conv_mfma <<<512, 512, 0, stream>>>(wb, xt, coef, bias, y1);
    k_style_fir <<<dim3(2, 2, 4096), 512, 0, stream>>>(y1, uf, df, out);
}

// Round 23
// 351.281 us; speedup vs baseline: 1.3789x; 1.0100x over previous
//
#include <hip/hip_runtime.h>
#include <hip/hip_bf16.h>

// StyleLayer: modulated conv3x3 as bf16 MFMA implicit GEMM (demod folded into
// input/output scales) + fused polyphase upfirdn(up2)->lrelu/clamp->upfirdn(down2).
// B=8, CIN=COUT=SDIM=512, H=W=64, K=3, taps=12, out 64x64. Conv out 66x66 (=4356 px).
// Round-23 = resubmit of round-22 (infra failure): conv/preps identical to
// r20/r21; fir phase-1 computes 4 adjacent outputs per thread (9 contiguous
// LDS reads -> 8 outputs, was 24 reads).

#define B_    8
#define CIN_  512
#define COUT_ 512
#define SDIM_ 512
#define H_    64
#define W_    64
#define HO_   66
#define NPIX  4356          // 66*66
#define XP    68            // padded input spatial (origin shift 2)

typedef short s8v  __attribute__((ext_vector_type(8)));   // 8 bf16 in 4 VGPRs
typedef float f4v  __attribute__((ext_vector_type(4)));

#define WAITV3() asm volatile("s_waitcnt vmcnt(3)" ::: "memory")
#define WAITV0() asm volatile("s_waitcnt vmcnt(0)" ::: "memory")

// ---------------- s[b,c] = w @ (aw/sqrt(SDIM)).T + ab ----------------
// one wave per output element; lane-strided coalesced loads + shuffle reduce.
__global__ __launch_bounds__(256) void k_style_s(
    const float* __restrict__ w, const float* __restrict__ aw,
    const float* __restrict__ ab, float* __restrict__ s) {
    const int t  = blockIdx.x * 4 + (threadIdx.x >> 6);   // 4096 outputs
    const int ln = threadIdx.x & 63;
    const int b = t >> 9, c = t & 511;
    const float* wp = w + b * SDIM_;
    const float* ap = aw + (size_t)c * SDIM_;
    float acc = 0.f;
    #pragma unroll
    for (int j = 0; j < 8; ++j) { int k = ln + 64 * j; acc += wp[k] * ap[k]; }
    #pragma unroll
    for (int off = 32; off; off >>= 1) acc += __shfl_down(acc, off, 64);
    if (ln == 0) s[t] = acc * 0.044194173824159216f + ab[c];
}

// ---------------- coef[b,o] = scale * rsqrt(sum_c s^2 r) * rsqrt(ema) ----------------
__global__ __launch_bounds__(256) void k_style_coef(
    const float* __restrict__ s, const float* __restrict__ r,
    const float* __restrict__ ema, float* __restrict__ coef) {
    const int t  = blockIdx.x * 4 + (threadIdx.x >> 6);   // 4096 outputs
    const int ln = threadIdx.x & 63;
    const int b = t >> 9, o = t & 511;
    const float* sp = s + b * 512;
    const float* rp = r + (size_t)o * 512;
    float acc = 0.f;
    #pragma unroll
    for (int j = 0; j < 8; ++j) {
        int k = ln + 64 * j;
        float sv = sp[k];
        acc += sv * sv * rp[k];
    }
    #pragma unroll
    for (int off = 32; off; off >>= 1) acc += __shfl_down(acc, off, 64);
    if (ln == 0) {
        float d  = rsqrtf(acc * (1.0f / 4608.0f) + 1e-8f);
        coef[t] = d * rsqrtf(ema[0]) * 0.014731391274719739f;
    }
}

// ---------------- wb[tap][o][c] = bf16(cw[o][c][tap]);  r[o*512+c] = sum_tap cw^2 ----
__global__ __launch_bounds__(256) void k_prep_w(const float* __restrict__ cw,
                                                __hip_bfloat16* __restrict__ wb,
                                                float* __restrict__ r) {
    __shared__ float sm[2304];
    const int base = blockIdx.x * 256;                // pair index o*512+c; 1024 blocks
    const int tid  = threadIdx.x;
    const float* src = cw + (size_t)base * 9;
    for (int i = tid; i < 2304; i += 256) sm[i] = src[i];
    __syncthreads();
    float a = 0.f;
    ushort u[9];
    #pragma unroll
    for (int k = 0; k < 9; ++k) {
        float v = sm[tid * 9 + k];                    // stride-9: conflict-free
        a += v * v;
        __hip_bfloat16 h = __float2bfloat16(v);
        u[k] = *reinterpret_cast<ushort*>(&h);
    }
    r[base + tid] = a;
    ushort* wbu = reinterpret_cast<ushort*>(wb);
    #pragma unroll
    for (int tap = 0; tap < 9; ++tap)
        wbu[tap * 262144 + base + tid] = u[tap];
}

// ---------------- xt[b][y][x][c] = bf16(x[b][c][y-2][x-2] * s[b][c]), zero pad ----
__global__ __launch_bounds__(256) void k_prep_x(const float* __restrict__ x,
                                                const float* __restrict__ s,
                                                __hip_bfloat16* __restrict__ xt) {
    __shared__ float tile[64][65];
    const int y = blockIdx.x;            // 0..67
    const int b = blockIdx.y;
    const int tid = threadIdx.x;
    const bool yin = (y >= 2 && y < 66);
    __hip_bfloat16* orow = xt + ((size_t)(b * XP + y)) * XP * 512;
    for (int c0 = 0; c0 < 512; c0 += 64) {
        if (yin) {
            for (int i = tid; i < 64 * 64; i += 256) {
                int c = i >> 6, xx = i & 63;
                tile[c][xx] = x[(((size_t)b * 512 + c0 + c) * 64 + (y - 2)) * 64 + xx]
                              * s[b * 512 + c0 + c];
            }
        }
        __syncthreads();
        for (int j = tid; j < 68 * 8; j += 256) {     // 68 x-positions, 8 c-groups of 8
            int xx = j >> 3, cg = j & 7;
            bool xin = yin && (xx >= 2 && xx < 66);
            union { ushort u[8]; float4 f4; } pk;
            #pragma unroll
            for (int k = 0; k < 8; ++k) {
                float v = xin ? tile[cg * 8 + k][xx - 2] : 0.f;
                __hip_bfloat16 h = __float2bfloat16(v);
                pk.u[k] = *reinterpret_cast<ushort*>(&h);
            }
            *reinterpret_cast<float4*>(orow + (size_t)xx * 512 + c0 + cg * 8) = pk.f4;
        }
        __syncthreads();
    }
}

// ---------------- MFMA implicit-GEMM conv ----------------
// 256 o x 128 px tile, 8 waves (512 thr), K = 9 taps x 512 c, BK=32.
// 3-buffer rotation, counted s_waitcnt vmcnt(3).
// Grid-quantization fix: 560 tiles on 512 blocks (2/CU exactly); the 48
// double-duty blocks are dispatched FIRST (6 per XCD) so their 2nd tile
// overlaps the main phase instead of trailing as a 48-block straggler round.
__device__ __forceinline__ void gload16u(const char* base, unsigned voff, void* l) {
    __builtin_amdgcn_global_load_lds(
        (const __attribute__((address_space(1))) unsigned*)(base + voff),
        (__attribute__((address_space(3))) unsigned*)l, 16, 0, 0);
}

__global__ __launch_bounds__(512) void k_conv_mfma(
    const __hip_bfloat16* __restrict__ wb, const __hip_bfloat16* __restrict__ xt,
    const float* __restrict__ coef, const float* __restrict__ bias,
    __hip_bfloat16* __restrict__ y1)
{
    __shared__ __hip_bfloat16 lds[3][12288];          // [buf][A(8192) | B(4096)]

    // block -> (xcd, j): bid<48 are double-duty (j 0..5), dispatched first.
    const int bid   = blockIdx.x;                     // 512 blocks
    const int dbl   = bid < 48;
    const int rr2   = dbl ? bid : bid - 48;
    const int xcd   = rr2 & 7;
    const int j     = dbl ? (rr2 >> 3) : (6 + (rr2 >> 3));   // 0..63 per XCD
    const int ntile = dbl ? 2 : 1;

    const int tid = threadIdx.x, wv = tid >> 6, ln = tid & 63;
    const int wm = wv >> 1, wn = wv & 1;              // 4 o-quadrants x 2 px-halves

    // ---- tile-invariant per-lane constants ----
    const int srow = tid >> 2, ssl = tid & 3;         // staging row 0..127, 16B slot
    const unsigned swzs = (unsigned)((ssl ^ ((srow >> 1) & 3)) << 3);
    int aoff[4], boff[4];
    #pragma unroll
    for (int f = 0; f < 4; ++f) {
        int r  = wm * 64 + f * 16 + (ln & 15);
        aoff[f] = (r * 32 + (((ln >> 4) ^ ((r >> 1) & 3)) << 3)) * 2;
        int rb = wn * 64 + f * 16 + (ln & 15);
        boff[f] = (8192 + rb * 32 + (((ln >> 4) ^ ((rb >> 1) & 3)) << 3)) * 2;
    }
    const char* wbB = (const char*)wb;

    for (int tt = 0; tt < ntile; ++tt) {
        const int pos  = (tt == 0) ? j : (64 + j);    // 0..69 within XCD range
        const int flat = xcd * 70 + pos;              // 0..559, bijective
        const int pi = flat % 35;
        const int t2 = flat / 35;                     // 0..15: (oi*8 + b)
        const int b  = t2 & 7;
        const int o0 = (t2 >> 3) * 256;
        const int p0 = pi * 128;

        // ---- per-tile staging offsets ----
        const char* xtB = (const char*)(xt + (size_t)b * XP * XP * 512);
        unsigned voffA0 = ((unsigned)(o0 + srow) * 512u + swzs) * 2u;
        unsigned voffA1 = ((unsigned)(o0 + 128 + srow) * 512u + swzs) * 2u;
        unsigned voffB0;
        {
            int p = p0 + srow; if (p > NPIX - 1) p = NPIX - 1;
            int py = (int)(((unsigned)p * 63551u) >> 22); // p/66
            int px = p - py * 66;
            voffB0 = ((unsigned)(py * XP + px) * 512u + swzs) * 2u;
        }

        f4v acc[4][4];
        #pragma unroll
        for (int fm = 0; fm < 4; ++fm)
            #pragma unroll
            for (int fn = 0; fn < 4; ++fn) acc[fm][fn] = (f4v){0.f, 0.f, 0.f, 0.f};

        auto stage = [&](int st, int buf) {           // buf is a literal at call sites
            int tap = st >> 4;                        // uniform -> SALU
            int ki  = (tap * 11) >> 5;                // tap/3 for tap<9
            int kj  = tap - ki * 3;
            unsigned ccb  = (unsigned)(st & 15) << 6; // c-chunk bytes
            unsigned offA = (unsigned)tap * 524288u + ccb;            // tap*512*512*2B
            unsigned offB = (unsigned)(ki * XP + kj) * 1024u + ccb;   // (ki*XP+kj)*512*2B
            __hip_bfloat16* dst = &lds[buf][0] + wv * 512;
            gload16u(wbB, voffA0 + offA, dst);        // A rows   0..127
            gload16u(wbB, voffA1 + offA, dst + 4096); // A rows 128..255
            gload16u(xtB, voffB0 + offB, dst + 8192); // B rows   0..127
        };

        auto compute = [&](int buf) {                 // buf literal -> const LDS bases
            const char* base = (const char*)&lds[buf][0];
            s8v af[4], bfv[4];
            #pragma unroll
            for (int f = 0; f < 4; ++f) {
                af[f]  = *reinterpret_cast<const s8v*>(base + aoff[f]);
                bfv[f] = *reinterpret_cast<const s8v*>(base + boff[f]);
            }
            #pragma unroll
            for (int fm = 0; fm < 4; ++fm)
                #pragma unroll
                for (int fn = 0; fn < 4; ++fn)
                    acc[fm][fn] = __builtin_amdgcn_mfma_f32_16x16x32_bf16(
                        af[fm], bfv[fn], acc[fm][fn], 0, 0, 0);
        };

        stage(0, 0);
        stage(1, 1);

        // steps 0..140 in groups of 3; counted vmcnt(3) keeps the next step's
        // 3 loads in flight across every barrier.
        #pragma unroll 1
        for (int st = 0; st < 141; st += 3) {
            WAITV3(); __builtin_amdgcn_s_barrier();
            compute(0); stage(st + 2, 2);
            WAITV3(); __builtin_amdgcn_s_barrier();
            compute(1); stage(st + 3, 0);
            WAITV3(); __builtin_amdgcn_s_barrier();
            compute(2); stage(st + 4, 1);
        }
        // epilogue: steps 141 (buf0), 142 (buf1), 143 (buf2; staged here).
        WAITV3(); __builtin_amdgcn_s_barrier();
        stage(143, 2); compute(0);
        WAITV3(); __builtin_amdgcn_s_barrier();
        compute(1);
        WAITV0(); __builtin_amdgcn_s_barrier();
        compute(2);

        // C-write: y1[b][o][p] bf16 = acc*coef + bias
        #pragma unroll
        for (int fm = 0; fm < 4; ++fm) {
            #pragma unroll
            for (int fn = 0; fn < 4; ++fn) {
                int p = p0 + wn * 64 + fn * 16 + (ln & 15);
                if (p < NPIX) {
                    int ob = o0 + wm * 64 + fm * 16 + (ln >> 4) * 4;
                    #pragma unroll
                    for (int jj = 0; jj < 4; ++jj) {
                        int o = ob + jj;
                        float v = acc[fm][fn][jj] * coef[b * 512 + o] + bias[o];
                        y1[((size_t)(b * 512 + o)) * NPIX + p] = __float2bfloat16(v);
                    }
                }
            }
        }
    }
}

// ---------------- fused upfirdn2(up2,pad(9,8)) -> lrelu*sqrt2,clamp -> upfirdn2(down2) ----
// 32x32 output tile, 512 threads. Phase 1: 4 adjacent h-outputs per thread
// (9 contiguous LDS reads feed 8 outputs; single pass, 420 active threads).
// Per-output FMA order identical -> bit-identical results.
__global__ __launch_bounds__(512) void k_style_fir(
    const __hip_bfloat16* __restrict__ y1, const float* __restrict__ uf,
    const float* __restrict__ df, float* __restrict__ out)
{
    __shared__ float smA[5632];          // It[42][44] then zt[74][76]
    __shared__ float smB[3200];          // hu[42][76] then dh[74][36]
    float* It = smA;                     // stride 44
    float* hu = smB;                     // stride 76
    float* zt = smA;                     // stride 76
    float* dh = smB;                     // stride 36

    const int img = blockIdx.z;          // b*COUT + o
    const int oy0 = blockIdx.y * 32;
    const int ox0 = blockIdx.x * 32;
    const int tid = threadIdx.x;
    const __hip_bfloat16* I = y1 + (size_t)img * NPIX;

    float cu[12], cd[12];
    #pragma unroll
    for (int q = 0; q < 12; ++q) { cu[q] = uf[q]; cd[q] = df[q]; }

    const int ty16 = tid >> 5, tx = tid & 31;   // 16 x 32
    const int ty32 = tid >> 4, tx4 = tid & 15;  // 32 x 16

    // phase 0: load It[42][42] <- y1 tile rows/cols [oy0-4, oy0+37]
    #pragma unroll
    for (int k = 0; k < 3; ++k) {
        int rr = ty16 + 16 * k; if (rr >= 42) break;
        int gy = oy0 - 4 + rr;
        bool yin = (gy >= 0 && gy < HO_);
        #pragma unroll
        for (int j = 0; j < 2; ++j) {
            int cc = tx + 32 * j; if (cc >= 42) continue;
            int gx = ox0 - 4 + cc;
            float v = 0.f;
            if (yin && gx >= 0 && gx < HO_) v = __bfloat162float(I[gy * HO_ + gx]);
            It[rr * 44 + cc] = v;
        }
    }
    __syncthreads();

    // phase 1: horizontal up-filter; thread t<420 owns (m = t/10, h = (t%10)*4
    // .. +3): 9 contiguous reads It[m][h..h+8] -> 4 float2 outputs.
    if (tid < 420) {
        int m  = tid / 10;
        int h0 = (tid - m * 10) * 4;
        float v9[9];
        #pragma unroll
        for (int q = 0; q < 9; ++q) v9[q] = It[m * 44 + h0 + q];
        #pragma unroll
        for (int jj = 0; jj < 4; ++jj) {
            int h = h0 + jj;
            if (h < 37) {
                float e = 0.f, o = 0.f;
                #pragma unroll
                for (int q = 0; q < 6; ++q) {
                    e += cu[2 * q] * v9[jj + 5 - q];
                    o += cu[2 * q + 1] * v9[jj + 5 - q];
                }
                *reinterpret_cast<float2*>(hu + m * 76 + 2 * h)
                    = make_float2(2.f * e, 2.f * o);
            }
        }
    }
    __syncthreads();

    // phase 2: vertical up-filter + lrelu*sqrt2 + clamp, sliding register
    // window down each column: 6 segments x 74 columns (7/6/6/6/6/6 row-pairs).
    {
        int rx  = tid % 74;
        int seg = tid / 74;              // 0..5 active; 68 threads idle
        if (seg < 6) {
            int r0  = (seg == 0) ? 0 : (1 + seg * 6);
            int cnt = (seg == 0) ? 7 : 6;
            float wnd[6];
            #pragma unroll
            for (int i = 0; i < 5; ++i) wnd[i] = hu[(r0 + i) * 76 + rx];
            #pragma unroll
            for (int i = 0; i < 7; ++i) {
                if (i < cnt) {
                    wnd[5] = hu[(r0 + i + 5) * 76 + rx];
                    float e = 0.f, o = 0.f;
                    #pragma unroll
                    for (int q = 0; q < 6; ++q) {
                        e += cu[2 * q] * wnd[5 - q];
                        o += cu[2 * q + 1] * wnd[5 - q];
                    }
                    e *= 2.f; o *= 2.f;
                    e = (e >= 0.f ? e : e * 0.2f) * 1.4142135623730951f;
                    o = (o >= 0.f ? o : o * 0.2f) * 1.4142135623730951f;
                    e = fminf(fmaxf(e, -256.f), 256.f);
                    o = fminf(fmaxf(o, -256.f), 256.f);
                    int r = r0 + i;
                    zt[(2 * r) * 76 + rx]     = e;
                    zt[(2 * r + 1) * 76 + rx] = o;
                    #pragma unroll
                    for (int k2 = 0; k2 < 5; ++k2) wnd[k2] = wnd[k2 + 1];
                }
            }
        }
    }
    __syncthreads();

    // phase 3: down horizontal (+decimate x), 2 adjacent outputs per 7 float2 reads.
    #pragma unroll
    for (int k = 0; k < 3; ++k) {
        int ry = ty32 + 32 * k; if (ry >= 74) break;
        const float* zr = zt + ry * 76 + 4 * tx4;
        float z[14];
        #pragma unroll
        for (int t = 0; t < 7; ++t) {
            float2 p2 = *reinterpret_cast<const float2*>(zr + 2 * t);
            z[2 * t] = p2.x; z[2 * t + 1] = p2.y;
        }
        float a0 = 0.f, a1 = 0.f;
        #pragma unroll
        for (int u = 0; u < 12; ++u) { a0 += z[u] * cd[11 - u]; a1 += z[u + 2] * cd[11 - u]; }
        *reinterpret_cast<float2*>(dh + ry * 36 + 2 * tx4) = make_float2(a0, a1);
    }
    __syncthreads();

    // phase 4: down vertical (+decimate y) + store, one row-pair per thread.
    {
        int r2 = ty16;                       // pair 0..15 -> oy rows (2r2, 2r2+1)
        float d[14];
        #pragma unroll
        for (int v = 0; v < 14; ++v) d[v] = dh[(4 * r2 + v) * 36 + tx];
        float a0 = 0.f, a1 = 0.f;
        #pragma unroll
        for (int v = 0; v < 12; ++v) { a0 += d[v] * cd[11 - v]; a1 += d[v + 2] * cd[11 - v]; }
        float* op = out + (size_t)img * 64 * 64 + (oy0 + 2 * r2) * 64 + ox0 + tx;
        op[0]  = a0;
        op[64] = a1;
    }
}

extern "C" void kernel_launch(void* const* d_in, const int* in_sizes, int n_in,
                              void* d_out, int out_size, void* d_ws, size_t ws_size,
                              hipStream_t stream) {
    const float* x    = (const float*)d_in[0];
    const float* w    = (const float*)d_in[1];
    const float* aw   = (const float*)d_in[2];
    const float* ab   = (const float*)d_in[3];
    const float* cw   = (const float*)d_in[4];
    const float* bias = (const float*)d_in[5];
    const float* uf   = (const float*)d_in[6];
    const float* df   = (const float*)d_in[7];
    const float* ema  = (const float*)d_in[8];
    float* out = (float*)d_out;

    float* ws   = (float*)d_ws;
    float* s_   = ws;                                   // 4096
    float* coef = ws + 4096;                            // 4096
    float* r_   = ws + 8192;                            // 262144
    // bf16 regions (sizes in float-slots): y1 8,921,088 | xt 9,469,952 | wb 1,179,648
    __hip_bfloat16* y1 = (__hip_bfloat16*)(ws + 270336);
    __hip_bfloat16* xt = (__hip_bfloat16*)(ws + 270336 + 8921088);
    __hip_bfloat16* wb = (__hip_bfloat16*)(ws + 270336 + 8921088 + 9469952);

    k_style_s   <<<1024, 256, 0, stream>>>(w, aw, ab, s_);
    k_prep_w    <<<1024, 256, 0, stream>>>(cw, wb, r_);
    k_style_coef<<<1024, 256, 0, stream>>>(s_, r_, ema, coef);
    k_prep_x    <<<dim3(68, 8), 256, 0, stream>>>(x, s_, xt);
    k_conv_mfma <<<512, 512, 0, stream>>>(wb, xt, coef, bias, y1);
    k_style_fir <<<dim3(2, 2, 4096), 512, 0, stream>>>(y1, uf, df, out);
}